// Round 1
// baseline (300.002 us; speedup 1.0000x reference)
//
#include <hip/hip_runtime.h>
#include <math.h>

#define NPG   8
#define IN_F  9
#define HID   64
#define HEADS 4
#define NEG   0.2f
#define GROUPS 8192

__device__ __forceinline__ float lrelu(float x){ return x >= 0.f ? x : NEG * x; }
__device__ __forceinline__ float eluf(float x){ return x > 0.f ? x : expm1f(x); }

// local edge index for src s -> dst d (s != d), per group; 56 edges
__device__ __forceinline__ int eidx(int s, int d){ return s*7 + (d < s ? d : d - 1); }

__global__ __launch_bounds__(256)
void gat_fused(const float* __restrict__ x,
               const float* __restrict__ ew_g,
               const float* __restrict__ W1,  const float* __restrict__ a_src1,
               const float* __restrict__ a_dst1, const float* __restrict__ We1,
               const float* __restrict__ a_e1, const float* __restrict__ b1,
               const float* __restrict__ W2,  const float* __restrict__ a_src2,
               const float* __restrict__ a_dst2, const float* __restrict__ We2,
               const float* __restrict__ a_e2, const float* __restrict__ b2,
               const float* __restrict__ Wr1, const float* __restrict__ br1,
               const float* __restrict__ Wr2, const float* __restrict__ br2,
               const float* __restrict__ Wc1, const float* __restrict__ bc1,
               const float* __restrict__ Wc2, const float* __restrict__ bc2,
               float* __restrict__ recon_out, float* __restrict__ cls_out)
{
    // stride 268 (== 12 mod 32) breaks row-stride bank conflicts
    __shared__ float buf[4][8][268];        // xp1 -> h1 -> xp2 (reused)
    __shared__ float alpha1s[4][HEADS][8][8]; // [w][h][dst][src]
    __shared__ float xw[4][72];
    __shared__ float ews[4][56];
    __shared__ float lws[4][8];
    __shared__ float als1[4][8][HEADS], ald1[4][8][HEADS];
    __shared__ float als2[4][8], ald2[4][8];
    __shared__ float alpha2s[4][8][8];
    __shared__ float embL[4][64];
    __shared__ float r1L[4][128];
    __shared__ float ces[8];                 // [0..3]=ce1[h], [4]=ce2

    const int tid  = threadIdx.x;
    const int wid  = tid >> 6;
    const int lane = tid & 63;
    const int n    = lane >> 3;   // node 0..7
    const int cg   = lane & 7;    // channel group 0..7
    const int g    = blockIdx.x * 4 + wid;

    // --- edge-feature scalars ce[h] = dot(We_h, a_e_h) (once per block) ---
    if (tid < 4) {
        float c = 0.f;
        for (int i = 0; i < HID; ++i) c = fmaf(We1[tid*HID + i], a_e1[tid*HID + i], c);
        ces[tid] = c;
    } else if (tid == 4) {
        float c = 0.f;
        for (int i = 0; i < HID; ++i) c = fmaf(We2[i], a_e2[i], c);
        ces[4] = c;
    }

    // --- S0: load x (8x9) and edge weights (56) for this group ---
    {
        const float* xg = x + (size_t)g * (NPG * IN_F);
        for (int i = lane; i < NPG * IN_F; i += 64) xw[wid][i] = xg[i];
        if (lane < 56) ews[wid][lane] = ew_g[(size_t)g * 56 + lane];
    }
    __syncthreads();

    // self-loop attr = mean of incoming edge weights (deg = 7)
    if (lane < 8) {
        const int d = lane; float s = 0.f;
        for (int ss = 0; ss < 8; ++ss)
            if (ss != d) s += ews[wid][eidx(ss, d)];
        lws[wid][d] = s * (1.f / 7.f);
    }
    __syncthreads();

    // --- S1: xp1 = x @ W1  (8 x 256); lane owns node n, cols {cg + 8j} ---
    {
        float xr[IN_F];
#pragma unroll
        for (int k = 0; k < IN_F; ++k) xr[k] = xw[wid][n * IN_F + k];
#pragma unroll 8
        for (int j = 0; j < 32; ++j) {
            const int c = cg + 8 * j;
            float a = 0.f;
#pragma unroll
            for (int k = 0; k < IN_F; ++k) a = fmaf(xr[k], W1[k * 256 + c], a);
            buf[wid][n][c] = a;
        }
    }
    __syncthreads();

    // --- S2: al_s1[n][h], al_d1[n][h] (dot over 64 ch, 2 lanes per pair) ---
    {
        const int p = lane >> 1, half = lane & 1;
        const int nn = p >> 2, h = p & 3;
        const int base = h * 64 + half * 32;
        float s = 0.f, d2 = 0.f;
#pragma unroll 8
        for (int i = 0; i < 32; ++i) {
            const float v = buf[wid][nn][base + i];
            s  = fmaf(v, a_src1[base + i], s);
            d2 = fmaf(v, a_dst1[base + i], d2);
        }
        s  += __shfl_xor(s, 1);
        d2 += __shfl_xor(d2, 1);
        if (!half) { als1[wid][nn][h] = s; ald1[wid][nn][h] = d2; }
    }
    __syncthreads();

    // --- S3: attention softmax layer1, lanes<32 handle (dst,h) ---
    if (lane < 32) {
        const int d = lane >> 2, h = lane & 3;
        const float ce = ces[h];
        const float ad = ald1[wid][d][h];
        float lg[8]; float mx = -1e30f;
#pragma unroll
        for (int ss = 0; ss < 8; ++ss) {
            const float w = (ss == d) ? lws[wid][d] : ews[wid][eidx(ss, d)];
            float t = als1[wid][ss][h] + ad + ce * w;
            t = lrelu(t);
            lg[ss] = t; mx = fmaxf(mx, t);
        }
        float sum = 0.f;
#pragma unroll
        for (int ss = 0; ss < 8; ++ss) { lg[ss] = expf(lg[ss] - mx); sum += lg[ss]; }
        const float inv = 1.f / (sum + 1e-16f);
#pragma unroll
        for (int ss = 0; ss < 8; ++ss) alpha1s[wid][h][d][ss] = lg[ss] * inv;
    }
    __syncthreads();

    // --- S4: out1[d] = sum_s alpha * xp1[s]; then +b1, ELU -> h1 (in buf) ---
    float h1v[32];
#pragma unroll
    for (int h = 0; h < 4; ++h) {
        float al[8];
#pragma unroll
        for (int ss = 0; ss < 8; ++ss) al[ss] = alpha1s[wid][h][n][ss];
#pragma unroll
        for (int jj = 0; jj < 8; ++jj) {
            const int j = h * 8 + jj;
            const int c = cg + 8 * j;
            float a = 0.f;
#pragma unroll
            for (int ss = 0; ss < 8; ++ss) a = fmaf(al[ss], buf[wid][ss][c], a);
            h1v[j] = a;
        }
    }
    __syncthreads();   // all xp1 reads complete before overwrite
#pragma unroll
    for (int j = 0; j < 32; ++j) {
        const int c = cg + 8 * j;
        buf[wid][n][c] = eluf(h1v[j] + b1[c]);
    }
    __syncthreads();

    // --- Layer2 GEMM: xp2 = h1 @ W2  (8x256 @ 256x64); lane: node n, cols cg*8..+7 ---
    float acc[8] = {0.f,0.f,0.f,0.f,0.f,0.f,0.f,0.f};
    {
        const float* w2p = W2 + cg * 8;
#pragma unroll 4
        for (int kq = 0; kq < 64; ++kq) {
            const float4 hv = *(const float4*)&buf[wid][n][4 * kq];
#pragma unroll
            for (int kk = 0; kk < 4; ++kk) {
                const int k = 4 * kq + kk;
                const float4 w0 = *(const float4*)(w2p + k * 64);
                const float4 w1 = *(const float4*)(w2p + k * 64 + 4);
                const float hk = (kk == 0) ? hv.x : (kk == 1) ? hv.y : (kk == 2) ? hv.z : hv.w;
                acc[0] = fmaf(hk, w0.x, acc[0]); acc[1] = fmaf(hk, w0.y, acc[1]);
                acc[2] = fmaf(hk, w0.z, acc[2]); acc[3] = fmaf(hk, w0.w, acc[3]);
                acc[4] = fmaf(hk, w1.x, acc[4]); acc[5] = fmaf(hk, w1.y, acc[5]);
                acc[6] = fmaf(hk, w1.z, acc[6]); acc[7] = fmaf(hk, w1.w, acc[7]);
            }
        }
    }
    // al_s2 / al_d2 (heads=1): partial dot + butterfly over cg lanes
    {
        float sp = 0.f, dp = 0.f;
#pragma unroll
        for (int i = 0; i < 8; ++i) {
            sp = fmaf(acc[i], a_src2[cg * 8 + i], sp);
            dp = fmaf(acc[i], a_dst2[cg * 8 + i], dp);
        }
        sp += __shfl_xor(sp, 1); sp += __shfl_xor(sp, 2); sp += __shfl_xor(sp, 4);
        dp += __shfl_xor(dp, 1); dp += __shfl_xor(dp, 2); dp += __shfl_xor(dp, 4);
        if (cg == 0) { als2[wid][n] = sp; ald2[wid][n] = dp; }
    }
    __syncthreads();   // all h1 reads done before xp2 overwrites buf
    *(float4*)&buf[wid][n][cg * 8]     = make_float4(acc[0], acc[1], acc[2], acc[3]);
    *(float4*)&buf[wid][n][cg * 8 + 4] = make_float4(acc[4], acc[5], acc[6], acc[7]);
    __syncthreads();

    // --- attention softmax layer2, lanes<8 handle dst ---
    if (lane < 8) {
        const int d = lane;
        const float ce = ces[4];
        const float ad = ald2[wid][d];
        float lg[8]; float mx = -1e30f;
#pragma unroll
        for (int ss = 0; ss < 8; ++ss) {
            const float w = (ss == d) ? lws[wid][d] : ews[wid][eidx(ss, d)];
            float t = als2[wid][ss] + ad + ce * w;
            t = lrelu(t);
            lg[ss] = t; mx = fmaxf(mx, t);
        }
        float sum = 0.f;
#pragma unroll
        for (int ss = 0; ss < 8; ++ss) { lg[ss] = expf(lg[ss] - mx); sum += lg[ss]; }
        const float inv = 1.f / (sum + 1e-16f);
#pragma unroll
        for (int ss = 0; ss < 8; ++ss) alpha2s[wid][d][ss] = lg[ss] * inv;
    }
    __syncthreads();

    // --- out2 + b2, ELU, mean-pool over 8 nodes -> emb ---
    float h2[8] = {0.f,0.f,0.f,0.f,0.f,0.f,0.f,0.f};
#pragma unroll
    for (int ss = 0; ss < 8; ++ss) {
        const float av = alpha2s[wid][n][ss];
        const float4 x0 = *(const float4*)&buf[wid][ss][cg * 8];
        const float4 x1 = *(const float4*)&buf[wid][ss][cg * 8 + 4];
        h2[0] = fmaf(av, x0.x, h2[0]); h2[1] = fmaf(av, x0.y, h2[1]);
        h2[2] = fmaf(av, x0.z, h2[2]); h2[3] = fmaf(av, x0.w, h2[3]);
        h2[4] = fmaf(av, x1.x, h2[4]); h2[5] = fmaf(av, x1.y, h2[5]);
        h2[6] = fmaf(av, x1.z, h2[6]); h2[7] = fmaf(av, x1.w, h2[7]);
    }
#pragma unroll
    for (int i = 0; i < 8; ++i) h2[i] = eluf(h2[i] + b2[cg * 8 + i]);
#pragma unroll
    for (int i = 0; i < 8; ++i) {
        float v = h2[i];
        v += __shfl_xor(v, 8); v += __shfl_xor(v, 16); v += __shfl_xor(v, 32);
        h2[i] = v * 0.125f;
    }
    if (lane < 8) {   // n==0 lanes: cg = lane
#pragma unroll
        for (int i = 0; i < 8; ++i) embL[wid][lane * 8 + i] = h2[i];
    }
    __syncthreads();

    // --- readout: r1 = relu(emb @ Wr1 + br1), 128 wide ---
    {
        float a0 = br1[lane], a1 = br1[64 + lane];
#pragma unroll 8
        for (int k = 0; k < 64; ++k) {
            const float e = embL[wid][k];
            a0 = fmaf(e, Wr1[k * 128 + lane], a0);
            a1 = fmaf(e, Wr1[k * 128 + 64 + lane], a1);
        }
        r1L[wid][lane]      = fmaxf(a0, 0.f);
        r1L[wid][64 + lane] = fmaxf(a1, 0.f);
    }
    __syncthreads();

    // --- recon = r1 @ Wr2 + br2  (72 wide) ---
    {
        const int c2 = 64 + (lane & 7);
        float a0 = br2[lane];      // lane < 64 < 72, safe
        float a1 = br2[c2];
#pragma unroll 8
        for (int k = 0; k < 128; ++k) {
            const float r = r1L[wid][k];
            a0 = fmaf(r, Wr2[k * 72 + lane], a0);
            a1 = fmaf(r, Wr2[k * 72 + c2], a1);
        }
        recon_out[(size_t)g * 72 + lane] = a0;
        if (lane < 8) recon_out[(size_t)g * 72 + c2] = a1;
    }

    // --- cls head: relu(emb @ Wc1 + bc1) @ Wc2 + bc2 ---
    if (lane < 32) {
        float a = bc1[lane];
#pragma unroll 8
        for (int k = 0; k < 64; ++k) a = fmaf(embL[wid][k], Wc1[k * 32 + lane], a);
        a = fmaxf(a, 0.f) * Wc2[lane];
        a += __shfl_xor(a, 1); a += __shfl_xor(a, 2); a += __shfl_xor(a, 4);
        a += __shfl_xor(a, 8); a += __shfl_xor(a, 16);
        if (lane == 0) cls_out[g] = a + bc2[0];
    }
}

extern "C" void kernel_launch(void* const* d_in, const int* in_sizes, int n_in,
                              void* d_out, int out_size, void* d_ws, size_t ws_size,
                              hipStream_t stream) {
    const float* x      = (const float*)d_in[0];
    // d_in[1] edge_index (int32)  — topology is analytic, unused
    const float* ew     = (const float*)d_in[2];
    // d_in[3] batch (int32)       — analytic, unused
    const float* W1     = (const float*)d_in[4];
    const float* a_src1 = (const float*)d_in[5];
    const float* a_dst1 = (const float*)d_in[6];
    const float* We1    = (const float*)d_in[7];
    const float* a_e1   = (const float*)d_in[8];
    const float* b1     = (const float*)d_in[9];
    const float* W2     = (const float*)d_in[10];
    const float* a_src2 = (const float*)d_in[11];
    const float* a_dst2 = (const float*)d_in[12];
    const float* We2    = (const float*)d_in[13];
    const float* a_e2   = (const float*)d_in[14];
    const float* b2     = (const float*)d_in[15];
    const float* Wr1    = (const float*)d_in[16];
    const float* br1    = (const float*)d_in[17];
    const float* Wr2    = (const float*)d_in[18];
    const float* br2    = (const float*)d_in[19];
    const float* Wc1    = (const float*)d_in[20];
    const float* bc1    = (const float*)d_in[21];
    const float* Wc2    = (const float*)d_in[22];
    const float* bc2    = (const float*)d_in[23];

    float* recon = (float*)d_out;
    float* cls   = (float*)d_out + (size_t)GROUPS * 72;

    dim3 grid(GROUPS / 4), block(256);
    hipLaunchKernelGGL(gat_fused, grid, block, 0, stream,
                       x, ew, W1, a_src1, a_dst1, We1, a_e1, b1,
                       W2, a_src2, a_dst2, We2, a_e2, b2,
                       Wr1, br1, Wr2, br2, Wc1, bc1, Wc2, bc2,
                       recon, cls);
}

// Round 2
// 121.543 us; speedup vs baseline: 2.4683x; 2.4683x over previous
//
#include <hip/hip_runtime.h>
#include <math.h>

#define NEG 0.2f
#define GROUPS 8192

typedef unsigned short u16;
typedef u16 ushort8 __attribute__((ext_vector_type(8)));

__device__ __forceinline__ float lrelu(float x){ return x >= 0.f ? x : NEG*x; }
__device__ __forceinline__ float eluf(float x){ return x > 0.f ? x : __expf(x) - 1.f; }
__device__ __forceinline__ int eidx(int s,int d){ return s*7 + (d<s ? d : d-1); }
__device__ __forceinline__ float bf2f(u16 u){
    union { unsigned i; float f; } v; v.i = ((unsigned)u)<<16; return v.f;
}
__device__ __forceinline__ u16 f2bf(float f){
    union { float f; unsigned i; } v; v.f = f;
    unsigned r = v.i + 0x7fffu + ((v.i>>16)&1u);
    return (u16)(r>>16);
}

// One wave (64 threads) per block, 2 groups per wave.
// lane = n*8 + cg  (n: node 0..7, cg: channel-group 0..7)
__global__ __launch_bounds__(64, 4)
void gat_fused2(const float* __restrict__ x, const float* __restrict__ ew_g,
    const float* __restrict__ W1, const float* __restrict__ a_src1,
    const float* __restrict__ a_dst1, const float* __restrict__ We1,
    const float* __restrict__ a_e1, const float* __restrict__ b1,
    const float* __restrict__ W2, const float* __restrict__ a_src2,
    const float* __restrict__ a_dst2, const float* __restrict__ We2,
    const float* __restrict__ a_e2, const float* __restrict__ b2,
    const float* __restrict__ Wr1, const float* __restrict__ br1,
    const float* __restrict__ Wr2, const float* __restrict__ br2,
    const float* __restrict__ Wc1, const float* __restrict__ bc1,
    const float* __restrict__ Wc2, const float* __restrict__ bc2,
    float* __restrict__ recon, float* __restrict__ cls)
{
    // stride 264 ushorts = 132 dwords == 4 (mod 32) -> conflict-free b128 LDS reads
    __shared__ __align__(16) u16 act[2][8][264];     // bf16: xp1 -> h1; f32 xp2 overlay later
    __shared__ __align__(16) float alpha1[2][4][8][8]; // [g][head][dst][src]
    __shared__ float als1[64], ald1[64];               // idx = g*32 + n*4 + h
    __shared__ float als2[2][8], ald2[2][8];
    __shared__ float alpha2[2][8][8];
    __shared__ float xw[2][72];
    __shared__ float ews2[2][56];
    __shared__ float lws[2][8];
    __shared__ __align__(16) float embs[2][64];
    __shared__ __align__(16) float r1s[2][132];
    __shared__ float ces[6];

    const int lane = threadIdx.x;       // 0..63
    const int n    = lane >> 3;
    const int cg   = lane & 7;
    const int g0   = blockIdx.x * 2;

    // --- edge-scalar ce[h] = dot(We_h, a_e_h) ---
    if (lane < 4) {
        float c = 0.f;
#pragma unroll 8
        for (int i = 0; i < 64; ++i) c = fmaf(We1[lane*64+i], a_e1[lane*64+i], c);
        ces[lane] = c;
    } else if (lane == 4) {
        float c = 0.f;
#pragma unroll 8
        for (int i = 0; i < 64; ++i) c = fmaf(We2[i], a_e2[i], c);
        ces[4] = c;
    }

    // --- load x (2x72) and edge weights (2x56) ---
    {
        const float* xg = x + (size_t)g0 * 72;
        for (int i = lane; i < 144; i += 64) (&xw[0][0])[i] = xg[i];
        const float* eg = ew_g + (size_t)g0 * 56;
        for (int i = lane; i < 112; i += 64) (&ews2[0][0])[i] = eg[i];
    }
    __syncthreads();

    // self-loop attr = mean of 7 incoming edge weights
    if (lane < 16) {
        const int g = lane >> 3, d = lane & 7;
        float s = 0.f;
#pragma unroll
        for (int ss = 0; ss < 8; ++ss) if (ss != d) s += ews2[g][eidx(ss, d)];
        lws[g][d] = s * (1.f/7.f);
    }

    // --- S1: xp1 = x @ W1 for both groups; lane owns cols {u*64 + cg*8 + 0..7} ---
    {
        float xr0[9], xr1[9];
#pragma unroll
        for (int k = 0; k < 9; ++k) { xr0[k] = xw[0][n*9+k]; xr1[k] = xw[1][n*9+k]; }
#pragma unroll
        for (int u = 0; u < 4; ++u) {
            const int cb = u*64 + cg*8;
            float a0[8] = {0,0,0,0,0,0,0,0}, a1[8] = {0,0,0,0,0,0,0,0};
#pragma unroll
            for (int k = 0; k < 9; ++k) {
                const float4 w0 = *(const float4*)(W1 + k*256 + cb);
                const float4 w1 = *(const float4*)(W1 + k*256 + cb + 4);
                const float f0 = xr0[k], f1 = xr1[k];
                a0[0]=fmaf(f0,w0.x,a0[0]); a0[1]=fmaf(f0,w0.y,a0[1]);
                a0[2]=fmaf(f0,w0.z,a0[2]); a0[3]=fmaf(f0,w0.w,a0[3]);
                a0[4]=fmaf(f0,w1.x,a0[4]); a0[5]=fmaf(f0,w1.y,a0[5]);
                a0[6]=fmaf(f0,w1.z,a0[6]); a0[7]=fmaf(f0,w1.w,a0[7]);
                a1[0]=fmaf(f1,w0.x,a1[0]); a1[1]=fmaf(f1,w0.y,a1[1]);
                a1[2]=fmaf(f1,w0.z,a1[2]); a1[3]=fmaf(f1,w0.w,a1[3]);
                a1[4]=fmaf(f1,w1.x,a1[4]); a1[5]=fmaf(f1,w1.y,a1[5]);
                a1[6]=fmaf(f1,w1.z,a1[6]); a1[7]=fmaf(f1,w1.w,a1[7]);
            }
            ushort8 p0, p1;
#pragma unroll
            for (int j = 0; j < 8; ++j) { p0[j] = f2bf(a0[j]); p1[j] = f2bf(a1[j]); }
            *(ushort8*)&act[0][n][cb] = p0;
            *(ushort8*)&act[1][n][cb] = p1;
        }
    }
    __syncthreads();

    // --- S2: attention dots; lane -> (g = lane>>5, n' = (lane>>2)&7, h = lane&3) ---
    {
        const int gg = lane >> 5, p = lane & 31, nn = p >> 2, hh = p & 3;
        const u16* ap = &act[gg][nn][hh*64];
        float s = 0.f, d2 = 0.f;
#pragma unroll
        for (int t = 0; t < 8; ++t) {
            const ushort8 v = *(const ushort8*)(ap + t*8);
            const float4 s0 = *(const float4*)(a_src1 + hh*64 + t*8);
            const float4 s1 = *(const float4*)(a_src1 + hh*64 + t*8 + 4);
            const float4 d0 = *(const float4*)(a_dst1 + hh*64 + t*8);
            const float4 d1 = *(const float4*)(a_dst1 + hh*64 + t*8 + 4);
            float f;
            f=bf2f(v[0]); s=fmaf(f,s0.x,s); d2=fmaf(f,d0.x,d2);
            f=bf2f(v[1]); s=fmaf(f,s0.y,s); d2=fmaf(f,d0.y,d2);
            f=bf2f(v[2]); s=fmaf(f,s0.z,s); d2=fmaf(f,d0.z,d2);
            f=bf2f(v[3]); s=fmaf(f,s0.w,s); d2=fmaf(f,d0.w,d2);
            f=bf2f(v[4]); s=fmaf(f,s1.x,s); d2=fmaf(f,d1.x,d2);
            f=bf2f(v[5]); s=fmaf(f,s1.y,s); d2=fmaf(f,d1.y,d2);
            f=bf2f(v[6]); s=fmaf(f,s1.z,s); d2=fmaf(f,d1.z,d2);
            f=bf2f(v[7]); s=fmaf(f,s1.w,s); d2=fmaf(f,d1.w,d2);
        }
        als1[lane] = s; ald1[lane] = d2;
    }
    __syncthreads();

    // --- S3: softmax layer1; lane -> (g, dst, h), all 64 lanes busy ---
    {
        const int gg = lane >> 5, dd = (lane >> 2) & 7, hh = lane & 3;
        const float ce = ces[hh], ad = ald1[gg*32 + dd*4 + hh];
        float lg[8], mx = -1e30f;
#pragma unroll
        for (int ss = 0; ss < 8; ++ss) {
            const float w = (ss == dd) ? lws[gg][dd] : ews2[gg][eidx(ss, dd)];
            float t = als1[gg*32 + ss*4 + hh] + ad + ce * w;
            t = lrelu(t);
            lg[ss] = t; mx = fmaxf(mx, t);
        }
        float sum = 0.f;
#pragma unroll
        for (int ss = 0; ss < 8; ++ss) { lg[ss] = __expf(lg[ss] - mx); sum += lg[ss]; }
        const float inv = 1.f / (sum + 1e-16f);
#pragma unroll
        for (int ss = 0; ss < 8; ++ss) alpha1[gg][hh][dd][ss] = lg[ss] * inv;
    }
    __syncthreads();

    // --- S4: h1 = ELU(alpha @ xp1 + b1), written back as bf16 (per group) ---
    for (int g = 0; g < 2; ++g) {
        float hv[32];
#pragma unroll
        for (int u = 0; u < 4; ++u) {
            const float4 al0 = *(const float4*)&alpha1[g][u][n][0];
            const float4 al1 = *(const float4*)&alpha1[g][u][n][4];
            float acc[8] = {0,0,0,0,0,0,0,0};
#pragma unroll
            for (int s = 0; s < 8; ++s) {
                const float av = (s==0)?al0.x:(s==1)?al0.y:(s==2)?al0.z:(s==3)?al0.w:
                                 (s==4)?al1.x:(s==5)?al1.y:(s==6)?al1.z:al1.w;
                const ushort8 v = *(const ushort8*)&act[g][s][u*64 + cg*8];
#pragma unroll
                for (int j = 0; j < 8; ++j) acc[j] = fmaf(av, bf2f(v[j]), acc[j]);
            }
#pragma unroll
            for (int j = 0; j < 8; ++j) hv[u*8+j] = acc[j];
        }
        __syncthreads();   // all reads of act[g] done before overwrite
#pragma unroll
        for (int u = 0; u < 4; ++u) {
            const int cb = u*64 + cg*8;
            const float4 b0 = *(const float4*)(b1 + cb);
            const float4 b2v = *(const float4*)(b1 + cb + 4);
            ushort8 p;
            p[0]=f2bf(eluf(hv[u*8+0]+b0.x)); p[1]=f2bf(eluf(hv[u*8+1]+b0.y));
            p[2]=f2bf(eluf(hv[u*8+2]+b0.z)); p[3]=f2bf(eluf(hv[u*8+3]+b0.w));
            p[4]=f2bf(eluf(hv[u*8+4]+b2v.x)); p[5]=f2bf(eluf(hv[u*8+5]+b2v.y));
            p[6]=f2bf(eluf(hv[u*8+6]+b2v.z)); p[7]=f2bf(eluf(hv[u*8+7]+b2v.w));
            *(ushort8*)&act[g][n][cb] = p;
        }
        __syncthreads();
    }

    // --- GEMM2: xp2 = h1 @ W2 (both groups share W2 loads); lane: node n, cols cg*8..+7 ---
    float acc0[8] = {0,0,0,0,0,0,0,0}, acc1[8] = {0,0,0,0,0,0,0,0};
    {
        const float* w2p = W2 + cg*8;
#pragma unroll 2
        for (int kq = 0; kq < 32; ++kq) {
            const ushort8 h0 = *(const ushort8*)&act[0][n][kq*8];
            const ushort8 h1 = *(const ushort8*)&act[1][n][kq*8];
#pragma unroll
            for (int kk = 0; kk < 8; ++kk) {
                const float* wr = w2p + (kq*8+kk)*64;
                const float4 w0 = *(const float4*)wr;
                const float4 w1 = *(const float4*)(wr + 4);
                const float f0 = bf2f(h0[kk]);
                const float f1 = bf2f(h1[kk]);
                acc0[0]=fmaf(f0,w0.x,acc0[0]); acc0[1]=fmaf(f0,w0.y,acc0[1]);
                acc0[2]=fmaf(f0,w0.z,acc0[2]); acc0[3]=fmaf(f0,w0.w,acc0[3]);
                acc0[4]=fmaf(f0,w1.x,acc0[4]); acc0[5]=fmaf(f0,w1.y,acc0[5]);
                acc0[6]=fmaf(f0,w1.z,acc0[6]); acc0[7]=fmaf(f0,w1.w,acc0[7]);
                acc1[0]=fmaf(f1,w0.x,acc1[0]); acc1[1]=fmaf(f1,w0.y,acc1[1]);
                acc1[2]=fmaf(f1,w0.z,acc1[2]); acc1[3]=fmaf(f1,w0.w,acc1[3]);
                acc1[4]=fmaf(f1,w1.x,acc1[4]); acc1[5]=fmaf(f1,w1.y,acc1[5]);
                acc1[6]=fmaf(f1,w1.z,acc1[6]); acc1[7]=fmaf(f1,w1.w,acc1[7]);
            }
        }
    }

    // --- al_s2 / al_d2 via dot + cg-butterfly ---
    {
        const float4 s0 = *(const float4*)(a_src2 + cg*8);
        const float4 s1 = *(const float4*)(a_src2 + cg*8 + 4);
        const float4 d0 = *(const float4*)(a_dst2 + cg*8);
        const float4 d1 = *(const float4*)(a_dst2 + cg*8 + 4);
        float sp0 = acc0[0]*s0.x + acc0[1]*s0.y + acc0[2]*s0.z + acc0[3]*s0.w
                  + acc0[4]*s1.x + acc0[5]*s1.y + acc0[6]*s1.z + acc0[7]*s1.w;
        float dp0 = acc0[0]*d0.x + acc0[1]*d0.y + acc0[2]*d0.z + acc0[3]*d0.w
                  + acc0[4]*d1.x + acc0[5]*d1.y + acc0[6]*d1.z + acc0[7]*d1.w;
        float sp1 = acc1[0]*s0.x + acc1[1]*s0.y + acc1[2]*s0.z + acc1[3]*s0.w
                  + acc1[4]*s1.x + acc1[5]*s1.y + acc1[6]*s1.z + acc1[7]*s1.w;
        float dp1 = acc1[0]*d0.x + acc1[1]*d0.y + acc1[2]*d0.z + acc1[3]*d0.w
                  + acc1[4]*d1.x + acc1[5]*d1.y + acc1[6]*d1.z + acc1[7]*d1.w;
        sp0 += __shfl_xor(sp0,1); sp0 += __shfl_xor(sp0,2); sp0 += __shfl_xor(sp0,4);
        dp0 += __shfl_xor(dp0,1); dp0 += __shfl_xor(dp0,2); dp0 += __shfl_xor(dp0,4);
        sp1 += __shfl_xor(sp1,1); sp1 += __shfl_xor(sp1,2); sp1 += __shfl_xor(sp1,4);
        dp1 += __shfl_xor(dp1,1); dp1 += __shfl_xor(dp1,2); dp1 += __shfl_xor(dp1,4);
        if (cg == 0) { als2[0][n]=sp0; ald2[0][n]=dp0; als2[1][n]=sp1; ald2[1][n]=dp1; }
    }
    __syncthreads();   // GEMM2 LDS reads + als2 writes complete

    // --- store xp2 (f32) overlaid on act region, row stride 68 floats ---
    float* xf0 = reinterpret_cast<float*>(&act[0][0][0]);
    float* xf1 = reinterpret_cast<float*>(&act[1][0][0]);
    *(float4*)(xf0 + n*68 + cg*8)     = make_float4(acc0[0],acc0[1],acc0[2],acc0[3]);
    *(float4*)(xf0 + n*68 + cg*8 + 4) = make_float4(acc0[4],acc0[5],acc0[6],acc0[7]);
    *(float4*)(xf1 + n*68 + cg*8)     = make_float4(acc1[0],acc1[1],acc1[2],acc1[3]);
    *(float4*)(xf1 + n*68 + cg*8 + 4) = make_float4(acc1[4],acc1[5],acc1[6],acc1[7]);
    __syncthreads();

    // --- softmax layer2; lanes<16 -> (g, dst) ---
    if (lane < 16) {
        const int g = lane >> 3, d = lane & 7;
        const float ce = ces[4], ad = ald2[g][d];
        float lg[8], mx = -1e30f;
#pragma unroll
        for (int ss = 0; ss < 8; ++ss) {
            const float w = (ss == d) ? lws[g][d] : ews2[g][eidx(ss, d)];
            float t = als2[g][ss] + ad + ce * w;
            t = lrelu(t);
            lg[ss] = t; mx = fmaxf(mx, t);
        }
        float sum = 0.f;
#pragma unroll
        for (int ss = 0; ss < 8; ++ss) { lg[ss] = __expf(lg[ss] - mx); sum += lg[ss]; }
        const float inv = 1.f / (sum + 1e-16f);
#pragma unroll
        for (int ss = 0; ss < 8; ++ss) alpha2[g][d][ss] = lg[ss] * inv;
    }
    __syncthreads();

    // --- aggregate2 + b2 + ELU + mean-pool -> embs ---
    float h2[2][8];
#pragma unroll
    for (int g = 0; g < 2; ++g) {
        const float* xf = g ? xf1 : xf0;
        float a[8] = {0,0,0,0,0,0,0,0};
#pragma unroll
        for (int ss = 0; ss < 8; ++ss) {
            const float av = alpha2[g][n][ss];
            const float4 v0 = *(const float4*)(xf + ss*68 + cg*8);
            const float4 v1 = *(const float4*)(xf + ss*68 + cg*8 + 4);
            a[0]=fmaf(av,v0.x,a[0]); a[1]=fmaf(av,v0.y,a[1]);
            a[2]=fmaf(av,v0.z,a[2]); a[3]=fmaf(av,v0.w,a[3]);
            a[4]=fmaf(av,v1.x,a[4]); a[5]=fmaf(av,v1.y,a[5]);
            a[6]=fmaf(av,v1.z,a[6]); a[7]=fmaf(av,v1.w,a[7]);
        }
        const float4 b0 = *(const float4*)(b2 + cg*8);
        const float4 b1v = *(const float4*)(b2 + cg*8 + 4);
        h2[g][0]=eluf(a[0]+b0.x); h2[g][1]=eluf(a[1]+b0.y);
        h2[g][2]=eluf(a[2]+b0.z); h2[g][3]=eluf(a[3]+b0.w);
        h2[g][4]=eluf(a[4]+b1v.x); h2[g][5]=eluf(a[5]+b1v.y);
        h2[g][6]=eluf(a[6]+b1v.z); h2[g][7]=eluf(a[7]+b1v.w);
    }
#pragma unroll
    for (int g = 0; g < 2; ++g)
#pragma unroll
        for (int j = 0; j < 8; ++j) {
            float v = h2[g][j];
            v += __shfl_xor(v, 8); v += __shfl_xor(v, 16); v += __shfl_xor(v, 32);
            h2[g][j] = v * 0.125f;
        }
    if (n == 0) {
#pragma unroll
        for (int g = 0; g < 2; ++g) {
            *(float4*)&embs[g][cg*8]     = make_float4(h2[g][0],h2[g][1],h2[g][2],h2[g][3]);
            *(float4*)&embs[g][cg*8 + 4] = make_float4(h2[g][4],h2[g][5],h2[g][6],h2[g][7]);
        }
    }
    __syncthreads();

    // --- r1 = relu(emb @ Wr1 + br1); lane owns cols {2*lane, 2*lane+1}, both groups ---
    {
        const int c = lane*2;
        float a00 = br1[c], a01 = br1[c+1];
        float a10 = a00,    a11 = a01;
#pragma unroll
        for (int kq = 0; kq < 16; ++kq) {
            const float4 e0 = *(const float4*)&embs[0][kq*4];
            const float4 e1 = *(const float4*)&embs[1][kq*4];
#pragma unroll
            for (int kk = 0; kk < 4; ++kk) {
                const float2 w = *(const float2*)(Wr1 + (kq*4+kk)*128 + c);
                const float f0 = (kk==0)?e0.x:(kk==1)?e0.y:(kk==2)?e0.z:e0.w;
                const float f1 = (kk==0)?e1.x:(kk==1)?e1.y:(kk==2)?e1.z:e1.w;
                a00 = fmaf(f0, w.x, a00); a01 = fmaf(f0, w.y, a01);
                a10 = fmaf(f1, w.x, a10); a11 = fmaf(f1, w.y, a11);
            }
        }
        r1s[0][c] = fmaxf(a00, 0.f); r1s[0][c+1] = fmaxf(a01, 0.f);
        r1s[1][c] = fmaxf(a10, 0.f); r1s[1][c+1] = fmaxf(a11, 0.f);
    }
    __syncthreads();

    // --- recon = r1 @ Wr2 + br2; lanes 0..35 own cols {2L, 2L+1} (72 cols), both groups ---
    if (lane < 36) {
        const int c = lane*2;
        float a00 = br2[c], a01 = br2[c+1];
        float a10 = a00,    a11 = a01;
#pragma unroll 8
        for (int kq = 0; kq < 32; ++kq) {
            const float4 r0 = *(const float4*)&r1s[0][kq*4];
            const float4 r1v = *(const float4*)&r1s[1][kq*4];
#pragma unroll
            for (int kk = 0; kk < 4; ++kk) {
                const float2 w = *(const float2*)(Wr2 + (kq*4+kk)*72 + c);
                const float f0 = (kk==0)?r0.x:(kk==1)?r0.y:(kk==2)?r0.z:r0.w;
                const float f1 = (kk==0)?r1v.x:(kk==1)?r1v.y:(kk==2)?r1v.z:r1v.w;
                a00 = fmaf(f0, w.x, a00); a01 = fmaf(f0, w.y, a01);
                a10 = fmaf(f1, w.x, a10); a11 = fmaf(f1, w.y, a11);
            }
        }
        *(float2*)(recon + (size_t)g0*72 + c)     = make_float2(a00, a01);
        *(float2*)(recon + (size_t)(g0+1)*72 + c) = make_float2(a10, a11);
    }

    // --- cls head ---
    if (lane < 32) {
        float a0 = bc1[lane], a1 = a0;
#pragma unroll
        for (int kq = 0; kq < 16; ++kq) {
            const float4 e0 = *(const float4*)&embs[0][kq*4];
            const float4 e1 = *(const float4*)&embs[1][kq*4];
#pragma unroll
            for (int kk = 0; kk < 4; ++kk) {
                const float w = Wc1[(kq*4+kk)*32 + lane];
                const float f0 = (kk==0)?e0.x:(kk==1)?e0.y:(kk==2)?e0.z:e0.w;
                const float f1 = (kk==0)?e1.x:(kk==1)?e1.y:(kk==2)?e1.z:e1.w;
                a0 = fmaf(f0, w, a0); a1 = fmaf(f1, w, a1);
            }
        }
        const float wc = Wc2[lane];
        a0 = fmaxf(a0, 0.f) * wc;
        a1 = fmaxf(a1, 0.f) * wc;
        a0 += __shfl_xor(a0,1); a0 += __shfl_xor(a0,2); a0 += __shfl_xor(a0,4);
        a0 += __shfl_xor(a0,8); a0 += __shfl_xor(a0,16);
        a1 += __shfl_xor(a1,1); a1 += __shfl_xor(a1,2); a1 += __shfl_xor(a1,4);
        a1 += __shfl_xor(a1,8); a1 += __shfl_xor(a1,16);
        if (lane == 0) { cls[g0] = a0 + bc2[0]; cls[g0+1] = a1 + bc2[0]; }
    }
}

extern "C" void kernel_launch(void* const* d_in, const int* in_sizes, int n_in,
                              void* d_out, int out_size, void* d_ws, size_t ws_size,
                              hipStream_t stream) {
    const float* x      = (const float*)d_in[0];
    const float* ew     = (const float*)d_in[2];
    const float* W1     = (const float*)d_in[4];
    const float* a_src1 = (const float*)d_in[5];
    const float* a_dst1 = (const float*)d_in[6];
    const float* We1    = (const float*)d_in[7];
    const float* a_e1   = (const float*)d_in[8];
    const float* b1     = (const float*)d_in[9];
    const float* W2     = (const float*)d_in[10];
    const float* a_src2 = (const float*)d_in[11];
    const float* a_dst2 = (const float*)d_in[12];
    const float* We2    = (const float*)d_in[13];
    const float* a_e2   = (const float*)d_in[14];
    const float* b2     = (const float*)d_in[15];
    const float* Wr1    = (const float*)d_in[16];
    const float* br1    = (const float*)d_in[17];
    const float* Wr2    = (const float*)d_in[18];
    const float* br2    = (const float*)d_in[19];
    const float* Wc1    = (const float*)d_in[20];
    const float* bc1    = (const float*)d_in[21];
    const float* Wc2    = (const float*)d_in[22];
    const float* bc2    = (const float*)d_in[23];

    float* recon = (float*)d_out;
    float* cls   = (float*)d_out + (size_t)GROUPS * 72;

    dim3 grid(GROUPS / 2), block(64);
    hipLaunchKernelGGL(gat_fused2, grid, block, 0, stream,
                       x, ew, W1, a_src1, a_dst1, We1, a_e1, b1,
                       W2, a_src2, a_dst2, We2, a_e2, b2,
                       Wr1, br1, Wr2, br2, Wc1, bc1, Wc2, bc2,
                       recon, cls);
}

// Round 3
// 70.738 us; speedup vs baseline: 4.2410x; 1.7182x over previous
//
#include <hip/hip_runtime.h>
#include <math.h>

#define NEG 0.2f
#define GROUPS 8192

typedef unsigned short u16;
typedef u16 ushort8 __attribute__((ext_vector_type(8)));
typedef short s16x8 __attribute__((ext_vector_type(8)));
typedef float f32x4 __attribute__((ext_vector_type(4)));

__device__ __forceinline__ float lrelu(float x){ return x >= 0.f ? x : NEG*x; }
__device__ __forceinline__ float eluf(float x){ return x > 0.f ? x : __expf(x) - 1.f; }
__device__ __forceinline__ int eidx(int s,int d){ return s*7 + (d<s ? d : d-1); }
__device__ __forceinline__ float bf2f(u16 u){
    union { unsigned i; float f; } v; v.i = ((unsigned)u)<<16; return v.f;
}
__device__ __forceinline__ u16 f2bf(float f){
    union { float f; unsigned i; } v; v.f = f;
    unsigned r = v.i + 0x7fffu + ((v.i>>16)&1u);
    return (u16)(r>>16);
}

// ---------------------------------------------------------------------------
// prep kernel: blocks 0..31 convert W2 (256x64 f32) into bf16 MFMA B-fragments
// (combo c = t*8+s; lane l holds W2[s*32+(l>>4)*8+j][t*16+(l&15)], j=0..7),
// block 32 computes the edge-attention scalars ce[].
// ---------------------------------------------------------------------------
__global__ __launch_bounds__(64)
void prep(const float* __restrict__ W2,
          const float* __restrict__ We1, const float* __restrict__ a_e1,
          const float* __restrict__ We2, const float* __restrict__ a_e2,
          u16* __restrict__ wfrag, float* __restrict__ ces)
{
    const int b = blockIdx.x, l = threadIdx.x;
    if (b < 32) {
        const int t = b >> 3, s = b & 7;
        const int c  = t*16 + (l & 15);
        const int k0 = s*32 + (l >> 4)*8;
        ushort8 p;
#pragma unroll
        for (int j = 0; j < 8; ++j) p[j] = f2bf(W2[(k0 + j)*64 + c]);
        *(ushort8*)(wfrag + (size_t)(b*64 + l)*8) = p;
    } else {
        if (l < 4) {
            float cacc = 0.f;
#pragma unroll 8
            for (int i = 0; i < 64; ++i) cacc = fmaf(We1[l*64+i], a_e1[l*64+i], cacc);
            ces[l] = cacc;
        } else if (l == 4) {
            float cacc = 0.f;
#pragma unroll 8
            for (int i = 0; i < 64; ++i) cacc = fmaf(We2[i], a_e2[i], cacc);
            ces[4] = cacc;
        }
    }
}

// ---------------------------------------------------------------------------
// One wave (64 threads) per block, 2 groups per wave.
// lane = n*8 + cg  (n: node 0..7, cg: channel-group 0..7)
// ---------------------------------------------------------------------------
__global__ __launch_bounds__(64, 4)
void gat_fused3(const float* __restrict__ x, const float* __restrict__ ew_g,
    const float* __restrict__ W1, const float* __restrict__ a_src1,
    const float* __restrict__ a_dst1, const float* __restrict__ b1,
    const float* __restrict__ a_src2, const float* __restrict__ a_dst2,
    const float* __restrict__ b2,
    const float* __restrict__ Wr1, const float* __restrict__ br1,
    const float* __restrict__ Wr2, const float* __restrict__ br2,
    const float* __restrict__ Wc1, const float* __restrict__ bc1,
    const float* __restrict__ Wc2, const float* __restrict__ bc2,
    const u16* __restrict__ wfrag, const float* __restrict__ cesg,
    float* __restrict__ recon, float* __restrict__ cls)
{
    // stride 264 ushorts = 132 dwords == 4 (mod 32) -> conflict-free b128 LDS reads
    __shared__ __align__(16) u16 act[2][8][264];       // bf16: xp1 -> h1; f32 xp2 overlay later
    __shared__ __align__(16) float alpha1[2][4][8][8]; // [g][head][dst][src]
    __shared__ float als1[64], ald1[64];               // idx = g*32 + n*4 + h
    __shared__ float als2[2][8], ald2[2][8];
    __shared__ float alpha2[2][8][8];
    __shared__ float xw[2][72];
    __shared__ float ews2[2][56];
    __shared__ float lws[2][8];
    __shared__ __align__(16) float embs[2][64];
    __shared__ __align__(16) float r1s[2][132];
    __shared__ float cesL[6];

    const int lane = threadIdx.x;       // 0..63
    const int n    = lane >> 3;
    const int cg   = lane & 7;
    const int g0   = blockIdx.x * 2;

    // --- load x (2x72), edge weights (2x56), ce scalars ---
    {
        const float* xg = x + (size_t)g0 * 72;
        for (int i = lane; i < 144; i += 64) (&xw[0][0])[i] = xg[i];
        const float* eg = ew_g + (size_t)g0 * 56;
        for (int i = lane; i < 112; i += 64) (&ews2[0][0])[i] = eg[i];
        if (lane < 6) cesL[lane] = cesg[lane];
    }
    __syncthreads();

    // self-loop attr = mean of 7 incoming edge weights
    if (lane < 16) {
        const int g = lane >> 3, d = lane & 7;
        float s = 0.f;
#pragma unroll
        for (int ss = 0; ss < 8; ++ss) if (ss != d) s += ews2[g][eidx(ss, d)];
        lws[g][d] = s * (1.f/7.f);
    }

    // --- S1: xp1 = x @ W1 for both groups; lane owns cols {u*64 + cg*8 + 0..7} ---
    {
        float xr0[9], xr1[9];
#pragma unroll
        for (int k = 0; k < 9; ++k) { xr0[k] = xw[0][n*9+k]; xr1[k] = xw[1][n*9+k]; }
#pragma unroll
        for (int u = 0; u < 4; ++u) {
            const int cb = u*64 + cg*8;
            float a0[8] = {0,0,0,0,0,0,0,0}, a1[8] = {0,0,0,0,0,0,0,0};
#pragma unroll
            for (int k = 0; k < 9; ++k) {
                const float4 w0 = *(const float4*)(W1 + k*256 + cb);
                const float4 w1 = *(const float4*)(W1 + k*256 + cb + 4);
                const float f0 = xr0[k], f1 = xr1[k];
                a0[0]=fmaf(f0,w0.x,a0[0]); a0[1]=fmaf(f0,w0.y,a0[1]);
                a0[2]=fmaf(f0,w0.z,a0[2]); a0[3]=fmaf(f0,w0.w,a0[3]);
                a0[4]=fmaf(f0,w1.x,a0[4]); a0[5]=fmaf(f0,w1.y,a0[5]);
                a0[6]=fmaf(f0,w1.z,a0[6]); a0[7]=fmaf(f0,w1.w,a0[7]);
                a1[0]=fmaf(f1,w0.x,a1[0]); a1[1]=fmaf(f1,w0.y,a1[1]);
                a1[2]=fmaf(f1,w0.z,a1[2]); a1[3]=fmaf(f1,w0.w,a1[3]);
                a1[4]=fmaf(f1,w1.x,a1[4]); a1[5]=fmaf(f1,w1.y,a1[5]);
                a1[6]=fmaf(f1,w1.z,a1[6]); a1[7]=fmaf(f1,w1.w,a1[7]);
            }
            ushort8 p0, p1;
#pragma unroll
            for (int j = 0; j < 8; ++j) { p0[j] = f2bf(a0[j]); p1[j] = f2bf(a1[j]); }
            *(ushort8*)&act[0][n][cb] = p0;
            *(ushort8*)&act[1][n][cb] = p1;
        }
    }
    __syncthreads();

    // --- S2: attention dots; lane -> (g = lane>>5, n' = (lane>>2)&7, h = lane&3) ---
    {
        const int gg = lane >> 5, p = lane & 31, nn = p >> 2, hh = p & 3;
        const u16* ap = &act[gg][nn][hh*64];
        float s = 0.f, d2 = 0.f;
#pragma unroll
        for (int t = 0; t < 8; ++t) {
            const ushort8 v = *(const ushort8*)(ap + t*8);
            const float4 s0 = *(const float4*)(a_src1 + hh*64 + t*8);
            const float4 s1 = *(const float4*)(a_src1 + hh*64 + t*8 + 4);
            const float4 d0 = *(const float4*)(a_dst1 + hh*64 + t*8);
            const float4 d1 = *(const float4*)(a_dst1 + hh*64 + t*8 + 4);
            float f;
            f=bf2f(v[0]); s=fmaf(f,s0.x,s); d2=fmaf(f,d0.x,d2);
            f=bf2f(v[1]); s=fmaf(f,s0.y,s); d2=fmaf(f,d0.y,d2);
            f=bf2f(v[2]); s=fmaf(f,s0.z,s); d2=fmaf(f,d0.z,d2);
            f=bf2f(v[3]); s=fmaf(f,s0.w,s); d2=fmaf(f,d0.w,d2);
            f=bf2f(v[4]); s=fmaf(f,s1.x,s); d2=fmaf(f,d1.x,d2);
            f=bf2f(v[5]); s=fmaf(f,s1.y,s); d2=fmaf(f,d1.y,d2);
            f=bf2f(v[6]); s=fmaf(f,s1.z,s); d2=fmaf(f,d1.z,d2);
            f=bf2f(v[7]); s=fmaf(f,s1.w,s); d2=fmaf(f,d1.w,d2);
        }
        als1[lane] = s; ald1[lane] = d2;
    }
    __syncthreads();

    // --- S3: softmax layer1; lane -> (g, dst, h), all 64 lanes busy ---
    {
        const int gg = lane >> 5, dd = (lane >> 2) & 7, hh = lane & 3;
        const float ce = cesL[hh], ad = ald1[gg*32 + dd*4 + hh];
        float lg[8], mx = -1e30f;
#pragma unroll
        for (int ss = 0; ss < 8; ++ss) {
            const float w = (ss == dd) ? lws[gg][dd] : ews2[gg][eidx(ss, dd)];
            float t = als1[gg*32 + ss*4 + hh] + ad + ce * w;
            t = lrelu(t);
            lg[ss] = t; mx = fmaxf(mx, t);
        }
        float sum = 0.f;
#pragma unroll
        for (int ss = 0; ss < 8; ++ss) { lg[ss] = __expf(lg[ss] - mx); sum += lg[ss]; }
        const float inv = 1.f / (sum + 1e-16f);
#pragma unroll
        for (int ss = 0; ss < 8; ++ss) alpha1[gg][hh][dd][ss] = lg[ss] * inv;
    }
    __syncthreads();

    // --- S4: h1 = ELU(alpha @ xp1 + b1), written back as bf16 (per group) ---
    for (int g = 0; g < 2; ++g) {
        float hv[32];
#pragma unroll
        for (int u = 0; u < 4; ++u) {
            const float4 al0 = *(const float4*)&alpha1[g][u][n][0];
            const float4 al1 = *(const float4*)&alpha1[g][u][n][4];
            float acc[8] = {0,0,0,0,0,0,0,0};
#pragma unroll
            for (int s = 0; s < 8; ++s) {
                const float av = (s==0)?al0.x:(s==1)?al0.y:(s==2)?al0.z:(s==3)?al0.w:
                                 (s==4)?al1.x:(s==5)?al1.y:(s==6)?al1.z:al1.w;
                const ushort8 v = *(const ushort8*)&act[g][s][u*64 + cg*8];
#pragma unroll
                for (int j = 0; j < 8; ++j) acc[j] = fmaf(av, bf2f(v[j]), acc[j]);
            }
#pragma unroll
            for (int j = 0; j < 8; ++j) hv[u*8+j] = acc[j];
        }
        __syncthreads();   // all reads of act[g] done before overwrite
#pragma unroll
        for (int u = 0; u < 4; ++u) {
            const int cb = u*64 + cg*8;
            const float4 b0 = *(const float4*)(b1 + cb);
            const float4 b2v = *(const float4*)(b1 + cb + 4);
            ushort8 p;
            p[0]=f2bf(eluf(hv[u*8+0]+b0.x)); p[1]=f2bf(eluf(hv[u*8+1]+b0.y));
            p[2]=f2bf(eluf(hv[u*8+2]+b0.z)); p[3]=f2bf(eluf(hv[u*8+3]+b0.w));
            p[4]=f2bf(eluf(hv[u*8+4]+b2v.x)); p[5]=f2bf(eluf(hv[u*8+5]+b2v.y));
            p[6]=f2bf(eluf(hv[u*8+6]+b2v.z)); p[7]=f2bf(eluf(hv[u*8+7]+b2v.w));
            *(ushort8*)&act[g][n][cb] = p;
        }
        __syncthreads();
    }

    // --- GEMM2 via MFMA: xp2[16][64] = h1[16][256] @ W2[256][64] (bf16 in, f32 acc)
    //     A row r = g*8+n' = lane&15, k-octet = lane>>4; B-frags preconverted in wfrag.
    f32x4 acc[4] = {{0,0,0,0},{0,0,0,0},{0,0,0,0},{0,0,0,0}};
    {
        const int r = lane & 15;
        const u16* arow = &act[r >> 3][r & 7][(lane >> 4) * 8];
#pragma unroll
        for (int s = 0; s < 8; ++s) {
            const s16x8 af = *(const s16x8*)(arow + s * 32);
#pragma unroll
            for (int t = 0; t < 4; ++t) {
                const s16x8 bf = *(const s16x8*)(wfrag + (size_t)(((t*8 + s)*64 + lane))*8);
                acc[t] = __builtin_amdgcn_mfma_f32_16x16x32_bf16(af, bf, acc[t], 0, 0, 0);
            }
        }
    }

    // --- al_s2 / al_d2 from C-layout (col = t*16 + (lane&15), row = 4*(lane>>4)+i) ---
    {
        const int c0 = lane & 15;
        float sp[4] = {0,0,0,0}, dp[4] = {0,0,0,0};
#pragma unroll
        for (int t = 0; t < 4; ++t) {
            const float as_ = a_src2[t*16 + c0];
            const float ad_ = a_dst2[t*16 + c0];
#pragma unroll
            for (int i = 0; i < 4; ++i) {
                sp[i] = fmaf(acc[t][i], as_, sp[i]);
                dp[i] = fmaf(acc[t][i], ad_, dp[i]);
            }
        }
#pragma unroll
        for (int i = 0; i < 4; ++i) {
            sp[i] += __shfl_xor(sp[i],1); sp[i] += __shfl_xor(sp[i],2);
            sp[i] += __shfl_xor(sp[i],4); sp[i] += __shfl_xor(sp[i],8);
            dp[i] += __shfl_xor(dp[i],1); dp[i] += __shfl_xor(dp[i],2);
            dp[i] += __shfl_xor(dp[i],4); dp[i] += __shfl_xor(dp[i],8);
        }
        if ((lane & 15) == 0) {
            const int rb = (lane >> 4) * 4;
#pragma unroll
            for (int i = 0; i < 4; ++i) {
                const int r = rb + i;
                als2[r >> 3][r & 7] = sp[i];
                ald2[r >> 3][r & 7] = dp[i];
            }
        }
    }
    __syncthreads();   // GEMM2 act reads + als2 writes complete

    // --- store xp2 (f32) overlaid on act region, row stride 68 floats ---
    float* xf0 = reinterpret_cast<float*>(&act[0][0][0]);
    float* xf1 = reinterpret_cast<float*>(&act[1][0][0]);
    {
        const int c0 = lane & 15;
#pragma unroll
        for (int t = 0; t < 4; ++t)
#pragma unroll
            for (int i = 0; i < 4; ++i) {
                const int r = (lane >> 4)*4 + i;
                float* xf = (r >> 3) ? xf1 : xf0;
                xf[(r & 7)*68 + t*16 + c0] = acc[t][i];
            }
    }
    __syncthreads();

    // --- softmax layer2; lanes<16 -> (g, dst) ---
    if (lane < 16) {
        const int g = lane >> 3, d = lane & 7;
        const float ce = cesL[4], ad = ald2[g][d];
        float lg[8], mx = -1e30f;
#pragma unroll
        for (int ss = 0; ss < 8; ++ss) {
            const float w = (ss == d) ? lws[g][d] : ews2[g][eidx(ss, d)];
            float t = als2[g][ss] + ad + ce * w;
            t = lrelu(t);
            lg[ss] = t; mx = fmaxf(mx, t);
        }
        float sum = 0.f;
#pragma unroll
        for (int ss = 0; ss < 8; ++ss) { lg[ss] = __expf(lg[ss] - mx); sum += lg[ss]; }
        const float inv = 1.f / (sum + 1e-16f);
#pragma unroll
        for (int ss = 0; ss < 8; ++ss) alpha2[g][d][ss] = lg[ss] * inv;
    }
    __syncthreads();

    // --- aggregate2 + b2 + ELU + mean-pool -> embs ---
    float h2[2][8];
#pragma unroll
    for (int g = 0; g < 2; ++g) {
        const float* xf = g ? xf1 : xf0;
        float a[8] = {0,0,0,0,0,0,0,0};
#pragma unroll
        for (int ss = 0; ss < 8; ++ss) {
            const float av = alpha2[g][n][ss];
            const float4 v0 = *(const float4*)(xf + ss*68 + cg*8);
            const float4 v1 = *(const float4*)(xf + ss*68 + cg*8 + 4);
            a[0]=fmaf(av,v0.x,a[0]); a[1]=fmaf(av,v0.y,a[1]);
            a[2]=fmaf(av,v0.z,a[2]); a[3]=fmaf(av,v0.w,a[3]);
            a[4]=fmaf(av,v1.x,a[4]); a[5]=fmaf(av,v1.y,a[5]);
            a[6]=fmaf(av,v1.z,a[6]); a[7]=fmaf(av,v1.w,a[7]);
        }
        const float4 b0 = *(const float4*)(b2 + cg*8);
        const float4 b1v = *(const float4*)(b2 + cg*8 + 4);
        h2[g][0]=eluf(a[0]+b0.x); h2[g][1]=eluf(a[1]+b0.y);
        h2[g][2]=eluf(a[2]+b0.z); h2[g][3]=eluf(a[3]+b0.w);
        h2[g][4]=eluf(a[4]+b1v.x); h2[g][5]=eluf(a[5]+b1v.y);
        h2[g][6]=eluf(a[6]+b1v.z); h2[g][7]=eluf(a[7]+b1v.w);
    }
#pragma unroll
    for (int g = 0; g < 2; ++g)
#pragma unroll
        for (int j = 0; j < 8; ++j) {
            float v = h2[g][j];
            v += __shfl_xor(v, 8); v += __shfl_xor(v, 16); v += __shfl_xor(v, 32);
            h2[g][j] = v * 0.125f;
        }
    if (n == 0) {
#pragma unroll
        for (int g = 0; g < 2; ++g) {
            *(float4*)&embs[g][cg*8]     = make_float4(h2[g][0],h2[g][1],h2[g][2],h2[g][3]);
            *(float4*)&embs[g][cg*8 + 4] = make_float4(h2[g][4],h2[g][5],h2[g][6],h2[g][7]);
        }
    }
    __syncthreads();

    // --- r1 = relu(emb @ Wr1 + br1); lane owns cols {2*lane, 2*lane+1}, both groups ---
    {
        const int c = lane*2;
        float a00 = br1[c], a01 = br1[c+1];
        float a10 = a00,    a11 = a01;
#pragma unroll
        for (int kq = 0; kq < 16; ++kq) {
            const float4 e0 = *(const float4*)&embs[0][kq*4];
            const float4 e1 = *(const float4*)&embs[1][kq*4];
#pragma unroll
            for (int kk = 0; kk < 4; ++kk) {
                const float2 w = *(const float2*)(Wr1 + (kq*4+kk)*128 + c);
                const float f0 = (kk==0)?e0.x:(kk==1)?e0.y:(kk==2)?e0.z:e0.w;
                const float f1 = (kk==0)?e1.x:(kk==1)?e1.y:(kk==2)?e1.z:e1.w;
                a00 = fmaf(f0, w.x, a00); a01 = fmaf(f0, w.y, a01);
                a10 = fmaf(f1, w.x, a10); a11 = fmaf(f1, w.y, a11);
            }
        }
        r1s[0][c] = fmaxf(a00, 0.f); r1s[0][c+1] = fmaxf(a01, 0.f);
        r1s[1][c] = fmaxf(a10, 0.f); r1s[1][c+1] = fmaxf(a11, 0.f);
    }
    __syncthreads();

    // --- recon = r1 @ Wr2 + br2; lanes 0..35 own cols {2L, 2L+1} (72 cols), both groups ---
    if (lane < 36) {
        const int c = lane*2;
        float a00 = br2[c], a01 = br2[c+1];
        float a10 = a00,    a11 = a01;
#pragma unroll 8
        for (int kq = 0; kq < 32; ++kq) {
            const float4 r0 = *(const float4*)&r1s[0][kq*4];
            const float4 r1v = *(const float4*)&r1s[1][kq*4];
#pragma unroll
            for (int kk = 0; kk < 4; ++kk) {
                const float2 w = *(const float2*)(Wr2 + (kq*4+kk)*72 + c);
                const float f0 = (kk==0)?r0.x:(kk==1)?r0.y:(kk==2)?r0.z:r0.w;
                const float f1 = (kk==0)?r1v.x:(kk==1)?r1v.y:(kk==2)?r1v.z:r1v.w;
                a00 = fmaf(f0, w.x, a00); a01 = fmaf(f0, w.y, a01);
                a10 = fmaf(f1, w.x, a10); a11 = fmaf(f1, w.y, a11);
            }
        }
        *(float2*)(recon + (size_t)g0*72 + c)     = make_float2(a00, a01);
        *(float2*)(recon + (size_t)(g0+1)*72 + c) = make_float2(a10, a11);
    }

    // --- cls head ---
    if (lane < 32) {
        float a0 = bc1[lane], a1 = a0;
#pragma unroll
        for (int kq = 0; kq < 16; ++kq) {
            const float4 e0 = *(const float4*)&embs[0][kq*4];
            const float4 e1 = *(const float4*)&embs[1][kq*4];
#pragma unroll
            for (int kk = 0; kk < 4; ++kk) {
                const float w = Wc1[(kq*4+kk)*32 + lane];
                const float f0 = (kk==0)?e0.x:(kk==1)?e0.y:(kk==2)?e0.z:e0.w;
                const float f1 = (kk==0)?e1.x:(kk==1)?e1.y:(kk==2)?e1.z:e1.w;
                a0 = fmaf(f0, w, a0); a1 = fmaf(f1, w, a1);
            }
        }
        const float wc = Wc2[lane];
        a0 = fmaxf(a0, 0.f) * wc;
        a1 = fmaxf(a1, 0.f) * wc;
        a0 += __shfl_xor(a0,1); a0 += __shfl_xor(a0,2); a0 += __shfl_xor(a0,4);
        a0 += __shfl_xor(a0,8); a0 += __shfl_xor(a0,16);
        a1 += __shfl_xor(a1,1); a1 += __shfl_xor(a1,2); a1 += __shfl_xor(a1,4);
        a1 += __shfl_xor(a1,8); a1 += __shfl_xor(a1,16);
        if (lane == 0) { cls[g0] = a0 + bc2[0]; cls[g0+1] = a1 + bc2[0]; }
    }
}

extern "C" void kernel_launch(void* const* d_in, const int* in_sizes, int n_in,
                              void* d_out, int out_size, void* d_ws, size_t ws_size,
                              hipStream_t stream) {
    const float* x      = (const float*)d_in[0];
    const float* ew     = (const float*)d_in[2];
    const float* W1     = (const float*)d_in[4];
    const float* a_src1 = (const float*)d_in[5];
    const float* a_dst1 = (const float*)d_in[6];
    const float* We1    = (const float*)d_in[7];
    const float* a_e1   = (const float*)d_in[8];
    const float* b1     = (const float*)d_in[9];
    const float* W2     = (const float*)d_in[10];
    const float* a_src2 = (const float*)d_in[11];
    const float* a_dst2 = (const float*)d_in[12];
    const float* We2    = (const float*)d_in[13];
    const float* a_e2   = (const float*)d_in[14];
    const float* b2     = (const float*)d_in[15];
    const float* Wr1    = (const float*)d_in[16];
    const float* br1    = (const float*)d_in[17];
    const float* Wr2    = (const float*)d_in[18];
    const float* br2    = (const float*)d_in[19];
    const float* Wc1    = (const float*)d_in[20];
    const float* bc1    = (const float*)d_in[21];
    const float* Wc2    = (const float*)d_in[22];
    const float* bc2    = (const float*)d_in[23];

    float* recon = (float*)d_out;
    float* cls   = (float*)d_out + (size_t)GROUPS * 72;

    u16*   wfrag = (u16*)d_ws;                          // 32 KB bf16 B-fragments
    float* ces   = (float*)((char*)d_ws + 32768);       // 6 floats

    hipLaunchKernelGGL(prep, dim3(33), dim3(64), 0, stream,
                       W2, We1, a_e1, We2, a_e2, wfrag, ces);

    hipLaunchKernelGGL(gat_fused3, dim3(GROUPS/2), dim3(64), 0, stream,
                       x, ew, W1, a_src1, a_dst1, b1,
                       a_src2, a_dst2, b2,
                       Wr1, br1, Wr2, br2, Wc1, bc1, Wc2, bc2,
                       wfrag, ces, recon, cls);
}

// Round 4
// 49.703 us; speedup vs baseline: 6.0359x; 1.4232x over previous
//
#include <hip/hip_runtime.h>
#include <math.h>

#define NEG 0.2f
#define GROUPS 8192

typedef unsigned short u16;
typedef u16 ushort8 __attribute__((ext_vector_type(8)));
typedef short s16x8 __attribute__((ext_vector_type(8)));
typedef float f32x4 __attribute__((ext_vector_type(4)));

__device__ __forceinline__ float lrelu(float x){ return x >= 0.f ? x : NEG*x; }
__device__ __forceinline__ float eluf(float x){ return x > 0.f ? x : __expf(x) - 1.f; }
__device__ __forceinline__ int eidx(int s,int d){ return s*7 + (d<s ? d : d-1); }
__device__ __forceinline__ float bf2f(u16 u){
    union { unsigned i; float f; } v; v.i = ((unsigned)u)<<16; return v.f;
}
__device__ __forceinline__ u16 f2bf(float f){
    union { float f; unsigned i; } v; v.f = f;
    unsigned r = v.i + 0x7fffu + ((v.i>>16)&1u);
    return (u16)(r>>16);
}

// ---------------------------------------------------------------------------
// prep: build bf16 MFMA B-fragments for W2 (32 frags), Wr1 (16), Wr2 (20,
// N padded 72->80), Wc1 (4); the W1s table (al_s/al_d folded into x-space);
// and the edge-attention scalars ce[].
// Fragment f (1 KB): lane l holds B[k0 + (l>>4)*8 + j][c0 + (l&15)], j=0..7.
// ---------------------------------------------------------------------------
__global__ __launch_bounds__(64)
void prep(const float* __restrict__ W1, const float* __restrict__ a_src1,
          const float* __restrict__ a_dst1, const float* __restrict__ W2,
          const float* __restrict__ Wr1, const float* __restrict__ Wr2,
          const float* __restrict__ Wc1,
          const float* __restrict__ We1, const float* __restrict__ a_e1,
          const float* __restrict__ We2, const float* __restrict__ a_e2,
          u16* __restrict__ wfrag, u16* __restrict__ wr1f,
          u16* __restrict__ wr2f, u16* __restrict__ wc1f,
          float* __restrict__ w1s, float* __restrict__ ces)
{
    const int b = blockIdx.x, l = threadIdx.x;
    const int c0 = l & 15, o = l >> 4;
    if (b < 32) {                       // W2: 256x64, f = t*8+s
        const int t = b >> 3, s = b & 7;
        ushort8 p;
#pragma unroll
        for (int j = 0; j < 8; ++j) p[j] = f2bf(W2[(s*32 + o*8 + j)*64 + t*16 + c0]);
        *(ushort8*)(wfrag + (size_t)(b*64 + l)*8) = p;
    } else if (b < 48) {                // Wr1: 64x128, f = ks*8+t
        const int f = b - 32, ks = f >> 3, t = f & 7;
        ushort8 p;
#pragma unroll
        for (int j = 0; j < 8; ++j) p[j] = f2bf(Wr1[(ks*32 + o*8 + j)*128 + t*16 + c0]);
        *(ushort8*)(wr1f + (size_t)(f*64 + l)*8) = p;
    } else if (b < 68) {                // Wr2: 128x72 (pad N->80), f = ks*5+t
        const int f = b - 48, ks = f / 5, t = f % 5;
        const int c = t*16 + c0;
        ushort8 p;
#pragma unroll
        for (int j = 0; j < 8; ++j)
            p[j] = (c < 72) ? f2bf(Wr2[(ks*32 + o*8 + j)*72 + c]) : (u16)0;
        *(ushort8*)(wr2f + (size_t)(f*64 + l)*8) = p;
    } else if (b < 72) {                // Wc1: 64x32, f = ks*2+t
        const int f = b - 68, ks = f >> 1, t = f & 1;
        ushort8 p;
#pragma unroll
        for (int j = 0; j < 8; ++j) p[j] = f2bf(Wc1[(ks*32 + o*8 + j)*32 + t*16 + c0]);
        *(ushort8*)(wc1f + (size_t)(f*64 + l)*8) = p;
    } else if (b == 72) {               // W1s[k][cc]: cc<4 -> src h=cc, cc>=4 -> dst
        for (int idx = l; idx < 72; idx += 64) {
            const int k = idx >> 3, cc = idx & 7, h = cc & 3;
            const float* av = (cc < 4) ? a_src1 : a_dst1;
            float acc = 0.f;
#pragma unroll 8
            for (int i = 0; i < 64; ++i) acc = fmaf(W1[k*256 + h*64 + i], av[h*64 + i], acc);
            w1s[idx] = acc;
        }
    } else {                            // ce scalars
        if (l < 4) {
            float c = 0.f;
#pragma unroll 8
            for (int i = 0; i < 64; ++i) c = fmaf(We1[l*64+i], a_e1[l*64+i], c);
            ces[l] = c;
        } else if (l == 4) {
            float c = 0.f;
#pragma unroll 8
            for (int i = 0; i < 64; ++i) c = fmaf(We2[i], a_e2[i], c);
            ces[4] = c;
        }
    }
}

// ---------------------------------------------------------------------------
// One wave (64 threads) per block, 2 groups per wave.
// lane = n*8 + cg  (n: node 0..7, cg: channel-group 0..7)
// ---------------------------------------------------------------------------
__global__ __launch_bounds__(64, 4)
void gat_fused4(const float* __restrict__ x, const float* __restrict__ ew_g,
    const float* __restrict__ W1, const float* __restrict__ b1,
    const float* __restrict__ a_src2, const float* __restrict__ a_dst2,
    const float* __restrict__ b2,
    const float* __restrict__ br1, const float* __restrict__ br2,
    const float* __restrict__ bc1, const float* __restrict__ Wc2,
    const float* __restrict__ bc2,
    const u16* __restrict__ wfrag, const u16* __restrict__ wr1f,
    const u16* __restrict__ wr2f, const u16* __restrict__ wc1f,
    const float* __restrict__ w1s, const float* __restrict__ cesg,
    float* __restrict__ recon, float* __restrict__ cls)
{
    // stride 264 ushorts = 132 dwords == 4 (mod 32) -> conflict-free b128 LDS reads
    __shared__ __align__(16) u16 act[2][8][264];       // bf16: xp1 -> h1; f32 xp2 overlay
    __shared__ __align__(16) float alpha1[2][4][8][8]; // [g][head][dst][src]
    __shared__ float als1[64], ald1[64];               // idx = g*32 + n*4 + h
    __shared__ float als2[2][8], ald2[2][8];
    __shared__ float alpha2[2][8][8];
    __shared__ float xw[2][72];
    __shared__ float ews2[2][56];
    __shared__ float lws[2][8];
    __shared__ float w1sL[72];
    __shared__ __align__(16) u16 embs16[2][64];
    __shared__ __align__(16) u16 r1s16[2][128];
    __shared__ float cesL[6];

    const int lane = threadIdx.x;       // 0..63
    const int n    = lane >> 3;
    const int cg   = lane & 7;
    const int g0   = blockIdx.x * 2;

    // --- load x (2x72), edge weights (2x56), W1s, ce scalars ---
    {
        const float* xg = x + (size_t)g0 * 72;
        for (int i = lane; i < 144; i += 64) (&xw[0][0])[i] = xg[i];
        const float* eg = ew_g + (size_t)g0 * 56;
        for (int i = lane; i < 112; i += 64) (&ews2[0][0])[i] = eg[i];
        for (int i = lane; i < 72; i += 64) w1sL[i] = w1s[i];
        if (lane < 6) cesL[lane] = cesg[lane];
    }
    __syncthreads();

    // self-loop attr = mean of 7 incoming edge weights
    if (lane < 16) {
        const int g = lane >> 3, d = lane & 7;
        float s = 0.f;
#pragma unroll
        for (int ss = 0; ss < 8; ++ss) if (ss != d) s += ews2[g][eidx(ss, d)];
        lws[g][d] = s * (1.f/7.f);
    }

    // --- S2': al_s1/al_d1 directly from x via W1s (f32-exact) ---
    {
        const int gg = lane >> 5, nn = (lane >> 2) & 7, hh = lane & 3;
        float s = 0.f, d = 0.f;
#pragma unroll
        for (int k = 0; k < 9; ++k) {
            const float xv = xw[gg][nn*9 + k];
            s = fmaf(xv, w1sL[k*8 + hh], s);
            d = fmaf(xv, w1sL[k*8 + 4 + hh], d);
        }
        als1[lane] = s; ald1[lane] = d;     // lane == gg*32 + nn*4 + hh
    }

    // --- S1: xp1 = x @ W1 for both groups; lane owns cols {u*64 + cg*8 + 0..7} ---
    {
        float xr0[9], xr1[9];
#pragma unroll
        for (int k = 0; k < 9; ++k) { xr0[k] = xw[0][n*9+k]; xr1[k] = xw[1][n*9+k]; }
#pragma unroll
        for (int u = 0; u < 4; ++u) {
            const int cb = u*64 + cg*8;
            float a0[8] = {0,0,0,0,0,0,0,0}, a1[8] = {0,0,0,0,0,0,0,0};
#pragma unroll
            for (int k = 0; k < 9; ++k) {
                const float4 w0 = *(const float4*)(W1 + k*256 + cb);
                const float4 w1 = *(const float4*)(W1 + k*256 + cb + 4);
                const float f0 = xr0[k], f1 = xr1[k];
                a0[0]=fmaf(f0,w0.x,a0[0]); a0[1]=fmaf(f0,w0.y,a0[1]);
                a0[2]=fmaf(f0,w0.z,a0[2]); a0[3]=fmaf(f0,w0.w,a0[3]);
                a0[4]=fmaf(f0,w1.x,a0[4]); a0[5]=fmaf(f0,w1.y,a0[5]);
                a0[6]=fmaf(f0,w1.z,a0[6]); a0[7]=fmaf(f0,w1.w,a0[7]);
                a1[0]=fmaf(f1,w0.x,a1[0]); a1[1]=fmaf(f1,w0.y,a1[1]);
                a1[2]=fmaf(f1,w0.z,a1[2]); a1[3]=fmaf(f1,w0.w,a1[3]);
                a1[4]=fmaf(f1,w1.x,a1[4]); a1[5]=fmaf(f1,w1.y,a1[5]);
                a1[6]=fmaf(f1,w1.z,a1[6]); a1[7]=fmaf(f1,w1.w,a1[7]);
            }
            ushort8 p0, p1;
#pragma unroll
            for (int j = 0; j < 8; ++j) { p0[j] = f2bf(a0[j]); p1[j] = f2bf(a1[j]); }
            *(ushort8*)&act[0][n][cb] = p0;
            *(ushort8*)&act[1][n][cb] = p1;
        }
    }
    __syncthreads();

    // --- S3: softmax layer1; lane -> (g, dst, h), all 64 lanes busy ---
    {
        const int gg = lane >> 5, dd = (lane >> 2) & 7, hh = lane & 3;
        const float ce = cesL[hh], ad = ald1[gg*32 + dd*4 + hh];
        float lg[8], mx = -1e30f;
#pragma unroll
        for (int ss = 0; ss < 8; ++ss) {
            const float w = (ss == dd) ? lws[gg][dd] : ews2[gg][eidx(ss, dd)];
            float t = als1[gg*32 + ss*4 + hh] + ad + ce * w;
            t = lrelu(t);
            lg[ss] = t; mx = fmaxf(mx, t);
        }
        float sum = 0.f;
#pragma unroll
        for (int ss = 0; ss < 8; ++ss) { lg[ss] = __expf(lg[ss] - mx); sum += lg[ss]; }
        const float inv = 1.f / (sum + 1e-16f);
#pragma unroll
        for (int ss = 0; ss < 8; ++ss) alpha1[gg][hh][dd][ss] = lg[ss] * inv;
    }
    __syncthreads();

    // --- S4: h1 = ELU(alpha @ xp1 + b1), written back as bf16 (per group) ---
    for (int g = 0; g < 2; ++g) {
        float hv[32];
#pragma unroll
        for (int u = 0; u < 4; ++u) {
            const float4 al0 = *(const float4*)&alpha1[g][u][n][0];
            const float4 al1 = *(const float4*)&alpha1[g][u][n][4];
            float acc[8] = {0,0,0,0,0,0,0,0};
#pragma unroll
            for (int s = 0; s < 8; ++s) {
                const float av = (s==0)?al0.x:(s==1)?al0.y:(s==2)?al0.z:(s==3)?al0.w:
                                 (s==4)?al1.x:(s==5)?al1.y:(s==6)?al1.z:al1.w;
                const ushort8 v = *(const ushort8*)&act[g][s][u*64 + cg*8];
#pragma unroll
                for (int j = 0; j < 8; ++j) acc[j] = fmaf(av, bf2f(v[j]), acc[j]);
            }
#pragma unroll
            for (int j = 0; j < 8; ++j) hv[u*8+j] = acc[j];
        }
        __syncthreads();   // all reads of act[g] done before overwrite
#pragma unroll
        for (int u = 0; u < 4; ++u) {
            const int cb = u*64 + cg*8;
            const float4 b0 = *(const float4*)(b1 + cb);
            const float4 b2v = *(const float4*)(b1 + cb + 4);
            ushort8 p;
            p[0]=f2bf(eluf(hv[u*8+0]+b0.x)); p[1]=f2bf(eluf(hv[u*8+1]+b0.y));
            p[2]=f2bf(eluf(hv[u*8+2]+b0.z)); p[3]=f2bf(eluf(hv[u*8+3]+b0.w));
            p[4]=f2bf(eluf(hv[u*8+4]+b2v.x)); p[5]=f2bf(eluf(hv[u*8+5]+b2v.y));
            p[6]=f2bf(eluf(hv[u*8+6]+b2v.z)); p[7]=f2bf(eluf(hv[u*8+7]+b2v.w));
            *(ushort8*)&act[g][n][cb] = p;
        }
        __syncthreads();
    }

    // --- GEMM2 via MFMA: xp2[16][64] = h1[16][256] @ W2 ---
    f32x4 acc[4] = {{0,0,0,0},{0,0,0,0},{0,0,0,0},{0,0,0,0}};
    {
        const int r = lane & 15;
        const u16* arow = &act[r >> 3][r & 7][(lane >> 4) * 8];
#pragma unroll
        for (int s = 0; s < 8; ++s) {
            const s16x8 af = *(const s16x8*)(arow + s * 32);
#pragma unroll
            for (int t = 0; t < 4; ++t) {
                const s16x8 bf = *(const s16x8*)(wfrag + (size_t)(((t*8 + s)*64 + lane))*8);
                acc[t] = __builtin_amdgcn_mfma_f32_16x16x32_bf16(af, bf, acc[t], 0, 0, 0);
            }
        }
    }

    // --- al_s2 / al_d2 from C-layout (col = t*16 + (lane&15), row = 4*(lane>>4)+i) ---
    {
        const int c0 = lane & 15;
        float sp[4] = {0,0,0,0}, dp[4] = {0,0,0,0};
#pragma unroll
        for (int t = 0; t < 4; ++t) {
            const float as_ = a_src2[t*16 + c0];
            const float ad_ = a_dst2[t*16 + c0];
#pragma unroll
            for (int i = 0; i < 4; ++i) {
                sp[i] = fmaf(acc[t][i], as_, sp[i]);
                dp[i] = fmaf(acc[t][i], ad_, dp[i]);
            }
        }
#pragma unroll
        for (int i = 0; i < 4; ++i) {
            sp[i] += __shfl_xor(sp[i],1); sp[i] += __shfl_xor(sp[i],2);
            sp[i] += __shfl_xor(sp[i],4); sp[i] += __shfl_xor(sp[i],8);
            dp[i] += __shfl_xor(dp[i],1); dp[i] += __shfl_xor(dp[i],2);
            dp[i] += __shfl_xor(dp[i],4); dp[i] += __shfl_xor(dp[i],8);
        }
        if ((lane & 15) == 0) {
            const int rb = (lane >> 4) * 4;
#pragma unroll
            for (int i = 0; i < 4; ++i) {
                const int r = rb + i;
                als2[r >> 3][r & 7] = sp[i];
                ald2[r >> 3][r & 7] = dp[i];
            }
        }
    }
    __syncthreads();   // GEMM2 act reads + als2 writes complete

    // --- store xp2 (f32) overlaid on act region, row stride 68 floats ---
    float* xf0 = reinterpret_cast<float*>(&act[0][0][0]);
    float* xf1 = reinterpret_cast<float*>(&act[1][0][0]);
    {
        const int c0 = lane & 15;
#pragma unroll
        for (int t = 0; t < 4; ++t)
#pragma unroll
            for (int i = 0; i < 4; ++i) {
                const int r = (lane >> 4)*4 + i;
                float* xf = (r >> 3) ? xf1 : xf0;
                xf[(r & 7)*68 + t*16 + c0] = acc[t][i];
            }
    }
    __syncthreads();

    // --- softmax layer2; lanes<16 -> (g, dst) ---
    if (lane < 16) {
        const int g = lane >> 3, d = lane & 7;
        const float ce = cesL[4], ad = ald2[g][d];
        float lg[8], mx = -1e30f;
#pragma unroll
        for (int ss = 0; ss < 8; ++ss) {
            const float w = (ss == d) ? lws[g][d] : ews2[g][eidx(ss, d)];
            float t = als2[g][ss] + ad + ce * w;
            t = lrelu(t);
            lg[ss] = t; mx = fmaxf(mx, t);
        }
        float sum = 0.f;
#pragma unroll
        for (int ss = 0; ss < 8; ++ss) { lg[ss] = __expf(lg[ss] - mx); sum += lg[ss]; }
        const float inv = 1.f / (sum + 1e-16f);
#pragma unroll
        for (int ss = 0; ss < 8; ++ss) alpha2[g][d][ss] = lg[ss] * inv;
    }
    __syncthreads();

    // --- aggregate2 + b2 + ELU + mean-pool -> embs16 (bf16) ---
    float h2[2][8];
#pragma unroll
    for (int g = 0; g < 2; ++g) {
        const float* xf = g ? xf1 : xf0;
        float a[8] = {0,0,0,0,0,0,0,0};
#pragma unroll
        for (int ss = 0; ss < 8; ++ss) {
            const float av = alpha2[g][n][ss];
            const float4 v0 = *(const float4*)(xf + ss*68 + cg*8);
            const float4 v1 = *(const float4*)(xf + ss*68 + cg*8 + 4);
            a[0]=fmaf(av,v0.x,a[0]); a[1]=fmaf(av,v0.y,a[1]);
            a[2]=fmaf(av,v0.z,a[2]); a[3]=fmaf(av,v0.w,a[3]);
            a[4]=fmaf(av,v1.x,a[4]); a[5]=fmaf(av,v1.y,a[5]);
            a[6]=fmaf(av,v1.z,a[6]); a[7]=fmaf(av,v1.w,a[7]);
        }
        const float4 b0 = *(const float4*)(b2 + cg*8);
        const float4 b1v = *(const float4*)(b2 + cg*8 + 4);
        h2[g][0]=eluf(a[0]+b0.x); h2[g][1]=eluf(a[1]+b0.y);
        h2[g][2]=eluf(a[2]+b0.z); h2[g][3]=eluf(a[3]+b0.w);
        h2[g][4]=eluf(a[4]+b1v.x); h2[g][5]=eluf(a[5]+b1v.y);
        h2[g][6]=eluf(a[6]+b1v.z); h2[g][7]=eluf(a[7]+b1v.w);
    }
#pragma unroll
    for (int g = 0; g < 2; ++g)
#pragma unroll
        for (int j = 0; j < 8; ++j) {
            float v = h2[g][j];
            v += __shfl_xor(v, 8); v += __shfl_xor(v, 16); v += __shfl_xor(v, 32);
            h2[g][j] = v * 0.125f;
        }
    if (n == 0) {       // lane < 8, cg = lane
#pragma unroll
        for (int g = 0; g < 2; ++g) {
            ushort8 p;
#pragma unroll
            for (int j = 0; j < 8; ++j) p[j] = f2bf(h2[g][j]);
            *(ushort8*)&embs16[g][lane*8] = p;
        }
    }
    __syncthreads();

    // --- readout via MFMA (M=2 rows used of 16) ---
    // A-frags of emb, kept for r1 and cls
    s16x8 aemb0 = {0,0,0,0,0,0,0,0}, aemb1 = {0,0,0,0,0,0,0,0};
    {
        const int r = lane & 15, o = lane >> 4;
        if (r < 2) {
            aemb0 = *(const s16x8*)&embs16[r][o*8];
            aemb1 = *(const s16x8*)&embs16[r][32 + o*8];
        }
    }
    // r1 = relu(emb @ Wr1 + br1) -> r1s16 (bf16)
    {
        f32x4 ar[8];
        const f32x4 z = {0,0,0,0};
#pragma unroll
        for (int t = 0; t < 8; ++t) ar[t] = z;
#pragma unroll
        for (int t = 0; t < 8; ++t) {
            ar[t] = __builtin_amdgcn_mfma_f32_16x16x32_bf16(
                aemb0, *(const s16x8*)(wr1f + (size_t)((0*8 + t)*64 + lane)*8), ar[t], 0,0,0);
            ar[t] = __builtin_amdgcn_mfma_f32_16x16x32_bf16(
                aemb1, *(const s16x8*)(wr1f + (size_t)((1*8 + t)*64 + lane)*8), ar[t], 0,0,0);
        }
        const int c0 = lane & 15, o = lane >> 4;
        if (o == 0) {
#pragma unroll
            for (int t = 0; t < 8; ++t) {
                const float bb = br1[t*16 + c0];
                r1s16[0][t*16 + c0] = f2bf(fmaxf(ar[t][0] + bb, 0.f));
                r1s16[1][t*16 + c0] = f2bf(fmaxf(ar[t][1] + bb, 0.f));
            }
        }
    }
    __syncthreads();

    // recon = r1 @ Wr2 + br2  (direct global store)
    {
        f32x4 ac[5];
        const f32x4 z = {0,0,0,0};
#pragma unroll
        for (int t = 0; t < 5; ++t) ac[t] = z;
        const int r = lane & 15, o = lane >> 4;
#pragma unroll
        for (int ks = 0; ks < 4; ++ks) {
            s16x8 a = {0,0,0,0,0,0,0,0};
            if (r < 2) a = *(const s16x8*)&r1s16[r][ks*32 + o*8];
#pragma unroll
            for (int t = 0; t < 5; ++t)
                ac[t] = __builtin_amdgcn_mfma_f32_16x16x32_bf16(
                    a, *(const s16x8*)(wr2f + (size_t)((ks*5 + t)*64 + lane)*8), ac[t], 0,0,0);
        }
        if (o == 0) {
            const int c0 = r;
#pragma unroll
            for (int t = 0; t < 5; ++t) {
                const int c = t*16 + c0;
                if (c < 72) {
                    const float bb = br2[c];
                    recon[(size_t)g0*72 + c]       = ac[t][0] + bb;
                    recon[(size_t)(g0+1)*72 + c]   = ac[t][1] + bb;
                }
            }
        }
    }

    // cls = relu(emb @ Wc1 + bc1) @ Wc2 + bc2
    {
        f32x4 ac[2];
        const f32x4 z = {0,0,0,0};
        ac[0] = z; ac[1] = z;
#pragma unroll
        for (int t = 0; t < 2; ++t) {
            ac[t] = __builtin_amdgcn_mfma_f32_16x16x32_bf16(
                aemb0, *(const s16x8*)(wc1f + (size_t)((0*2 + t)*64 + lane)*8), ac[t], 0,0,0);
            ac[t] = __builtin_amdgcn_mfma_f32_16x16x32_bf16(
                aemb1, *(const s16x8*)(wc1f + (size_t)((1*2 + t)*64 + lane)*8), ac[t], 0,0,0);
        }
        const int c0 = lane & 15;
        const float bb0 = bc1[c0], bb1 = bc1[16 + c0];
        const float wc0 = Wc2[c0], wc1v = Wc2[16 + c0];
        float p0 = fmaxf(ac[0][0] + bb0, 0.f)*wc0 + fmaxf(ac[1][0] + bb1, 0.f)*wc1v;
        float p1 = fmaxf(ac[0][1] + bb0, 0.f)*wc0 + fmaxf(ac[1][1] + bb1, 0.f)*wc1v;
        p0 += __shfl_xor(p0,1); p0 += __shfl_xor(p0,2); p0 += __shfl_xor(p0,4); p0 += __shfl_xor(p0,8);
        p1 += __shfl_xor(p1,1); p1 += __shfl_xor(p1,2); p1 += __shfl_xor(p1,4); p1 += __shfl_xor(p1,8);
        if (lane == 0) { cls[g0] = p0 + bc2[0]; cls[g0+1] = p1 + bc2[0]; }
    }
}

extern "C" void kernel_launch(void* const* d_in, const int* in_sizes, int n_in,
                              void* d_out, int out_size, void* d_ws, size_t ws_size,
                              hipStream_t stream) {
    const float* x      = (const float*)d_in[0];
    const float* ew     = (const float*)d_in[2];
    const float* W1     = (const float*)d_in[4];
    const float* a_src1 = (const float*)d_in[5];
    const float* a_dst1 = (const float*)d_in[6];
    const float* We1    = (const float*)d_in[7];
    const float* a_e1   = (const float*)d_in[8];
    const float* b1     = (const float*)d_in[9];
    const float* W2     = (const float*)d_in[10];
    const float* a_src2 = (const float*)d_in[11];
    const float* a_dst2 = (const float*)d_in[12];
    const float* We2    = (const float*)d_in[13];
    const float* a_e2   = (const float*)d_in[14];
    const float* b2     = (const float*)d_in[15];
    const float* Wr1    = (const float*)d_in[16];
    const float* br1    = (const float*)d_in[17];
    const float* Wr2    = (const float*)d_in[18];
    const float* br2    = (const float*)d_in[19];
    const float* Wc1    = (const float*)d_in[20];
    const float* bc1    = (const float*)d_in[21];
    const float* Wc2    = (const float*)d_in[22];
    const float* bc2    = (const float*)d_in[23];

    float* recon = (float*)d_out;
    float* cls   = (float*)d_out + (size_t)GROUPS * 72;

    char* ws = (char*)d_ws;
    u16*   wfrag = (u16*)(ws + 0);          // 32 KB
    u16*   wr1f  = (u16*)(ws + 32768);      // 16 KB
    u16*   wr2f  = (u16*)(ws + 49152);      // 20 KB
    u16*   wc1f  = (u16*)(ws + 69632);      // 4 KB
    float* w1s   = (float*)(ws + 73728);    // 288 B
    float* ces   = (float*)(ws + 74016);    // 24 B

    hipLaunchKernelGGL(prep, dim3(74), dim3(64), 0, stream,
                       W1, a_src1, a_dst1, W2, Wr1, Wr2, Wc1,
                       We1, a_e1, We2, a_e2,
                       wfrag, wr1f, wr2f, wc1f, w1s, ces);

    hipLaunchKernelGGL(gat_fused4, dim3(GROUPS/2), dim3(64), 0, stream,
                       x, ew, W1, b1, a_src2, a_dst2, b2,
                       br1, br2, bc1, Wc2, bc2,
                       wfrag, wr1f, wr2f, wc1f, w1s, ces,
                       recon, cls);
}